// Round 1
// baseline (745.710 us; speedup 1.0000x reference)
//
#include <hip/hip_runtime.h>

// Problem constants (match reference)
#define NX_ 432
#define NY_ 496
#define C_  64
#define B_  4
#define CELLS_ (NX_ * NY_)            // 214272 cells per (bin, batch) canvas plane
#define PLANE_ ((size_t)CELLS_)       // c-plane stride in floats
#define BATCH_STRIDE_ ((size_t)C_ * CELLS_)        // 13,713,408 floats
#define BIN_STRIDE_   ((size_t)B_ * C_ * CELLS_)   // 54,853,632 floats
#define MAP_BIN_ ((size_t)B_ * CELLS_)             // map entries per bin

// ---------------------------------------------------------------------------
// Kernel 1: scatter pillar index p into map[bin][b*CELLS + z + y*NX + x]
// coords layout per row: [b, z, y, x] int32. Cells are unique per sample.
// ---------------------------------------------------------------------------
__global__ __launch_bounds__(256) void scatter_idx_kernel(
    const int* __restrict__ coords0,
    const int* __restrict__ coords1,
    const int* __restrict__ coords2,
    int* __restrict__ map, int npil)
{
    const int bin = blockIdx.y;
    const int p = blockIdx.x * 256 + threadIdx.x;
    if (p >= npil) return;
    const int* coords = (bin == 0) ? coords0 : (bin == 1) ? coords1 : coords2;
    // 16B-aligned int4 row load
    int4 c = ((const int4*)coords)[p];
    size_t idx = (size_t)bin * MAP_BIN_ + (size_t)c.x * CELLS_ + c.y + c.z * NX_ + c.w;
    map[idx] = p;
}

// ---------------------------------------------------------------------------
// Kernel 2: dense gather pass. Each thread owns 4 consecutive cells; writes
// all 64 c-planes with coalesced float4 stores. Pillar reads stream
// sequentially per thread (pf[idx*64 + c], c++) -> L1 line reuse.
// ---------------------------------------------------------------------------
__global__ __launch_bounds__(256) void gather_kernel(
    const float* __restrict__ pf0,
    const float* __restrict__ pf1,
    const float* __restrict__ pf2,
    const int* __restrict__ map,
    float* __restrict__ out)
{
    const int bin = blockIdx.z;
    const int b   = blockIdx.y;
    const int cell = blockIdx.x * 1024 + threadIdx.x * 4;
    if (cell >= CELLS_) return;

    const float* __restrict__ pf = (bin == 0) ? pf0 : (bin == 1) ? pf1 : pf2;

    const int* m = map + (size_t)bin * MAP_BIN_ + (size_t)b * CELLS_ + cell;
    int4 idx = *(const int4*)m;

    const float* r0 = pf + (size_t)idx.x * C_;
    const float* r1 = pf + (size_t)idx.y * C_;
    const float* r2 = pf + (size_t)idx.z * C_;
    const float* r3 = pf + (size_t)idx.w * C_;
    const bool v0 = idx.x >= 0, v1 = idx.y >= 0, v2 = idx.z >= 0, v3 = idx.w >= 0;

    float* o = out + (size_t)bin * BIN_STRIDE_ + (size_t)b * BATCH_STRIDE_ + cell;

#pragma unroll 8
    for (int c = 0; c < C_; ++c) {
        float4 v;
        v.x = v0 ? r0[c] : 0.0f;
        v.y = v1 ? r1[c] : 0.0f;
        v.z = v2 ? r2[c] : 0.0f;
        v.w = v3 ? r3[c] : 0.0f;
        *(float4*)(o + (size_t)c * PLANE_) = v;
    }
}

// ---------------------------------------------------------------------------
// Fallback path (only if ws_size too small): zero output, direct scatter.
// Correct but suffers write amplification.
// ---------------------------------------------------------------------------
__global__ __launch_bounds__(256) void direct_scatter_kernel(
    const float* __restrict__ pf0, const int* __restrict__ co0,
    const float* __restrict__ pf1, const int* __restrict__ co1,
    const float* __restrict__ pf2, const int* __restrict__ co2,
    float* __restrict__ out, int npil)
{
    const int bin = blockIdx.y;
    const int t = blockIdx.x * 256 + threadIdx.x;
    const int p = t >> 6;        // pillar
    const int c = t & 63;        // feature
    if (p >= npil) return;
    const float* pf = (bin == 0) ? pf0 : (bin == 1) ? pf1 : pf2;
    const int* co = (bin == 0) ? co0 : (bin == 1) ? co1 : co2;
    int4 cd = ((const int4*)co)[p];
    size_t cell = (size_t)cd.y + cd.z * NX_ + cd.w;
    out[(size_t)bin * BIN_STRIDE_ + (size_t)cd.x * BATCH_STRIDE_ + (size_t)c * PLANE_ + cell] =
        pf[(size_t)p * C_ + c];
}

extern "C" void kernel_launch(void* const* d_in, const int* in_sizes, int n_in,
                              void* d_out, int out_size, void* d_ws, size_t ws_size,
                              hipStream_t stream) {
    const float* pf0 = (const float*)d_in[0];
    const int*   co0 = (const int*)d_in[1];
    const float* pf1 = (const float*)d_in[2];
    const int*   co1 = (const int*)d_in[3];
    const float* pf2 = (const float*)d_in[4];
    const int*   co2 = (const int*)d_in[5];
    float* out = (float*)d_out;

    const int npil = in_sizes[1] / 4;   // rows in coords (B*P_PER)

    const size_t map_bytes = 3 * MAP_BIN_ * sizeof(int);

    if (ws_size >= map_bytes) {
        int* map = (int*)d_ws;
        // init map to -1 (0xFFFFFFFF)
        hipMemsetAsync(map, 0xFF, map_bytes, stream);

        dim3 g1((npil + 255) / 256, 3, 1);
        scatter_idx_kernel<<<g1, 256, 0, stream>>>(co0, co1, co2, map, npil);

        dim3 g2((CELLS_ + 1023) / 1024, B_, 3);
        gather_kernel<<<g2, 256, 0, stream>>>(pf0, pf1, pf2, map, out);
    } else {
        // Fallback: zero + direct scatter
        hipMemsetAsync(out, 0, (size_t)out_size * sizeof(float), stream);
        dim3 g((npil * 64 + 255) / 256, 3, 1);
        direct_scatter_kernel<<<g, 256, 0, stream>>>(pf0, co0, pf1, co1, pf2, co2, out, npil);
    }
}

// Round 3
// 698.249 us; speedup vs baseline: 1.0680x; 1.0680x over previous
//
#include <hip/hip_runtime.h>

// Problem constants (match reference)
#define NX_ 432
#define NY_ 496
#define C_  64
#define B_  4
#define CELLS_ (NX_ * NY_)            // 214272 cells per (bin, batch) canvas plane
#define PLANE_ ((size_t)CELLS_)       // c-plane stride in floats
#define BATCH_STRIDE_ ((size_t)C_ * CELLS_)        // 13,713,408 floats
#define BIN_STRIDE_   ((size_t)B_ * C_ * CELLS_)   // 54,853,632 floats
#define MAP_BIN_ ((size_t)B_ * CELLS_)             // map entries per bin

// native clang vector type — accepted by __builtin_nontemporal_store
typedef float vfloat4 __attribute__((ext_vector_type(4)));
typedef int   vint4   __attribute__((ext_vector_type(4)));

// ---------------------------------------------------------------------------
// Kernel 1: scatter pillar index p into map[bin][b*CELLS + z + y*NX + x]
// coords layout per row: [b, z, y, x] int32. Cells are unique per sample.
// ---------------------------------------------------------------------------
__global__ __launch_bounds__(256) void scatter_idx_kernel(
    const int* __restrict__ coords0,
    const int* __restrict__ coords1,
    const int* __restrict__ coords2,
    int* __restrict__ map, int npil)
{
    const int bin = blockIdx.y;
    const int p = blockIdx.x * 256 + threadIdx.x;
    if (p >= npil) return;
    const int* coords = (bin == 0) ? coords0 : (bin == 1) ? coords1 : coords2;
    vint4 c = ((const vint4*)coords)[p];
    size_t idx = (size_t)bin * MAP_BIN_ + (size_t)c.x * CELLS_ + c.y + c.z * NX_ + c.w;
    map[idx] = p;
}

// ---------------------------------------------------------------------------
// Kernel 2: dense gather pass. Each thread owns 4 consecutive cells; writes
// all 64 c-planes with coalesced float4 nontemporal stores.
//
// Branchless loads: invalid idx (<0) is clamped to row 0 (always-safe
// address), loaded unconditionally (pipelined global_load, no exec-mask
// branches), then zero is selected in with v_cndmask AFTER the load.
// ---------------------------------------------------------------------------
__global__ __launch_bounds__(256) void gather_kernel(
    const float* __restrict__ pf0,
    const float* __restrict__ pf1,
    const float* __restrict__ pf2,
    const int* __restrict__ map,
    float* __restrict__ out)
{
    const int bin = blockIdx.z;
    const int b   = blockIdx.y;
    const int cell = blockIdx.x * 1024 + threadIdx.x * 4;
    if (cell >= CELLS_) return;

    const float* __restrict__ pf = (bin == 0) ? pf0 : (bin == 1) ? pf1 : pf2;

    const int* m = map + (size_t)bin * MAP_BIN_ + (size_t)b * CELLS_ + cell;
    vint4 idx = *(const vint4*)m;

    const bool v0 = idx.x >= 0, v1 = idx.y >= 0, v2 = idx.z >= 0, v3 = idx.w >= 0;
    // Clamp to row 0 so the address is always in-bounds -> unconditional loads.
    const float* r0 = pf + (size_t)(v0 ? idx.x : 0) * C_;
    const float* r1 = pf + (size_t)(v1 ? idx.y : 0) * C_;
    const float* r2 = pf + (size_t)(v2 ? idx.z : 0) * C_;
    const float* r3 = pf + (size_t)(v3 ? idx.w : 0) * C_;

    float* o = out + (size_t)bin * BIN_STRIDE_ + (size_t)b * BATCH_STRIDE_ + cell;

#pragma unroll 4
    for (int c = 0; c < C_; ++c) {
        // Unconditional loads (pipeline under vmcnt), select after.
        float x0 = r0[c];
        float x1 = r1[c];
        float x2 = r2[c];
        float x3 = r3[c];
        vfloat4 v;
        v.x = v0 ? x0 : 0.0f;
        v.y = v1 ? x1 : 0.0f;
        v.z = v2 ? x2 : 0.0f;
        v.w = v3 ? x3 : 0.0f;
        __builtin_nontemporal_store(v, (vfloat4*)(o + (size_t)c * PLANE_));
    }
}

extern "C" void kernel_launch(void* const* d_in, const int* in_sizes, int n_in,
                              void* d_out, int out_size, void* d_ws, size_t ws_size,
                              hipStream_t stream) {
    const float* pf0 = (const float*)d_in[0];
    const int*   co0 = (const int*)d_in[1];
    const float* pf1 = (const float*)d_in[2];
    const int*   co1 = (const int*)d_in[3];
    const float* pf2 = (const float*)d_in[4];
    const int*   co2 = (const int*)d_in[5];
    float* out = (float*)d_out;

    const int npil = in_sizes[1] / 4;   // rows in coords (B*P_PER)

    int* map = (int*)d_ws;
    const size_t map_bytes = 3 * MAP_BIN_ * sizeof(int);

    // init map to -1 (0xFFFFFFFF) — ~10 MB, ~2 us
    (void)hipMemsetAsync(map, 0xFF, map_bytes, stream);

    dim3 g1((npil + 255) / 256, 3, 1);
    scatter_idx_kernel<<<g1, 256, 0, stream>>>(co0, co1, co2, map, npil);

    dim3 g2((CELLS_ + 1023) / 1024, B_, 3);
    gather_kernel<<<g2, 256, 0, stream>>>(pf0, pf1, pf2, map, out);
}